// Round 6
// baseline (391.781 us; speedup 1.0000x reference)
//
#include <hip/hip_runtime.h>
#include <stdint.h>

#define M_TOK 256
#define K_IN  4096
#define N_OUT 11008
#define K_EXT 4160              // 4096 + 16 lora + 48 zero pad
#define ROWB  (K_EXT * 2)       // bytes per x_ext row = 8320
#define GRID  1376              // 8 xcd * 4 mg * 43 ngl  (wave-tile 64M x 32N)

typedef __attribute__((ext_vector_type(8))) short s16x8;
typedef __attribute__((ext_vector_type(8))) unsigned short u16x8;
typedef __attribute__((ext_vector_type(4))) float f32x4;

#define VMW(n) asm volatile("s_waitcnt vmcnt(" #n ")" ::: "memory")

static __device__ __forceinline__ unsigned cvt_pk_bf16(float lo, float hi) {
  unsigned r;
  asm("v_cvt_pk_bf16_f32 %0, %1, %2" : "=v"(r) : "v"(lo), "v"(hi));
  return r;
}

__device__ __forceinline__ unsigned short f2bf(float f) {
  union { float f; unsigned int u; } v; v.f = f;
  unsigned int u = v.u;
  u += 0x7fffu + ((u >> 16) & 1u);   // RNE
  return (unsigned short)(u >> 16);
}

// ---- prep: x fp32 -> bf16 row (stride K_EXT) + lora t2 appended as cols 4096.. ----
__global__ __launch_bounds__(512) void prep_kernel(
    const float* __restrict__ x, const float* __restrict__ la,
    unsigned short* __restrict__ xe)
{
  const int m   = blockIdx.x;
  const int tid = threadIdx.x;
  const int k   = tid * 8;
  const float* xr = x + (size_t)m * K_IN;
  unsigned short* xer = xe + (size_t)m * K_EXT;

  const float4 f0 = *(const float4*)(xr + k);
  const float4 f1 = *(const float4*)(xr + k + 4);
  u16x8 o;
  o[0] = f2bf(f0.x); o[1] = f2bf(f0.y); o[2] = f2bf(f0.z); o[3] = f2bf(f0.w);
  o[4] = f2bf(f1.x); o[5] = f2bf(f1.y); o[6] = f2bf(f1.z); o[7] = f2bf(f1.w);
  *(u16x8*)(xer + k) = o;

  if (tid >= 464) xer[K_IN + 16 + (tid - 464)] = 0;   // zero pad cols 4112..4159

  // lora: wave w owns r = 2w, 2w+1
  const int wave = tid >> 6, lane = tid & 63;
  const float* a0p = la + (size_t)(wave * 2) * K_IN;
  const float* a1p = a0p + K_IN;
  float s0 = 0.f, s1 = 0.f;
  #pragma unroll 4
  for (int it = 0; it < 16; ++it) {
    const int kk = it * 256 + lane * 4;
    const float4 xv = *(const float4*)(xr + kk);
    const float4 a0 = *(const float4*)(a0p + kk);
    const float4 a1 = *(const float4*)(a1p + kk);
    s0 += xv.x * a0.x + xv.y * a0.y + xv.z * a0.z + xv.w * a0.w;
    s1 += xv.x * a1.x + xv.y * a1.y + xv.z * a1.z + xv.w * a1.w;
  }
  #pragma unroll
  for (int off = 32; off > 0; off >>= 1) {
    s0 += __shfl_down(s0, off);
    s1 += __shfl_down(s1, off);
  }
  if (lane == 0) {
    xer[K_IN + wave * 2]     = f2bf(2.0f * s0);   // SCALING folded
    xer[K_IN + wave * 2 + 1] = f2bf(2.0f * s1);
  }
}

// ---------------- main: barrier-free independent-wave GEMM ----------------
// 1 wave per block. Wave-tile 64M x 32N, BK=64, 65 steps.
// A: x in wave-private LDS (glds, double-buffered, XOR-swizzled) - no sync needed.
// B: qweight dequantized straight into MFMA B-fragments in registers (depth-2).
// ZERO barriers anywhere. Counted vmcnt only.
__global__ __launch_bounds__(64, 2) void gptq_lora_gemm(
    const int* __restrict__ qw, const float* __restrict__ sc,
    const int* __restrict__ zr, const float* __restrict__ lb,
    const unsigned short* __restrict__ xe, float* __restrict__ out)
{
  __shared__ unsigned short xs[2][64 * 64];   // 2 x 8 KB, XOR-swizzled rows

  const int lane = threadIdx.x;
  const int bid  = blockIdx.x;
  // XCD-aware swizzle: 4 mg-blocks sharing a q-tile are bid-adjacent (same XCD)
  const int xcd = bid & 7;
  const int w   = bid >> 3;
  const int mg  = w & 3;          // 0..3 -> 64 M-rows
  const int ngl = w >> 2;         // 0..42
  const int ng  = xcd * 43 + ngl; // 0..343 -> 32 N-cols
  const int n0  = ng * 32;
  const int m0  = mg * 64;

  const int alo   = lane & 15;
  const int kb_hi = (lane >> 4) * 16;       // byte offset within 128B row slice
  const int koff  = (lane >> 4) * 8;        // int (k) offset for B loads

  const int n0c = n0 + alo;                 // B col for nf=0
  const int n1c = n0c + 16;                 // B col for nf=1
  const int* rowq0 = qw + (size_t)n0c * K_IN + koff;
  const int* rowq1 = qw + (size_t)n1c * K_IN + koff;

  f32x4 acc[4][2];
  #pragma unroll
  for (int i = 0; i < 4; ++i) { acc[i][0] = (f32x4)0.f; acc[i][1] = (f32x4)0.f; }

  s16x8 bbv[4];                   // B frags: [0]=nf0ks0 [1]=nf0ks1 [2]=nf1ks0 [3]=nf1ks1
  const char* xb = (const char*)xe;

  // ---- A staging: wave-private, linear LDS dest + inverse-swizzled source ----
  auto stage_x = [&](int buf, int step) {
    #pragma unroll
    for (int i = 0; i < 8; ++i) {
      const int base = i * 1024;
      const int o    = base + lane * 16;
      const int mrow = o >> 7;               // 0..63
      const int kb   = o & 127;
      const char* src = xb + (size_t)(m0 + mrow) * ROWB + step * 128
                           + (kb ^ ((mrow & 7) << 4));
      __builtin_amdgcn_global_load_lds(
          (const __attribute__((address_space(1))) void*)src,
          (__attribute__((address_space(3))) void*)((char*)xs[buf] + base),
          16, 0, 0);
    }
  };

  struct SZ { float s0, s1; int z0, z1; };

  // 8x dwordx4 q + 4 s/z loads = 12 vm per call
  auto loadB = [&](int t, int4 br[4][2], SZ& sz) {
    const int* p0 = rowq0 + t * 64;
    const int* p1 = rowq1 + t * 64;
    br[0][0] = *(const int4*)(p0);
    br[0][1] = *(const int4*)(p0 + 4);
    br[1][0] = *(const int4*)(p0 + 32);
    br[1][1] = *(const int4*)(p0 + 36);
    br[2][0] = *(const int4*)(p1);
    br[2][1] = *(const int4*)(p1 + 4);
    br[3][0] = *(const int4*)(p1 + 32);
    br[3][1] = *(const int4*)(p1 + 36);
    const int g = t >> 1;                    // GROUP_SIZE=128 = 2 k-steps
    sz.s0 = sc[(size_t)n0c * 32 + g];
    sz.z0 = zr[(size_t)n0c * 32 + g];
    sz.s1 = sc[(size_t)n1c * 32 + g];
    sz.z1 = zr[(size_t)n1c * 32 + g];
  };

  union BBu { s16x8 v; unsigned u[4]; };

  #define DQH(q, sS, zN, U0, U1) {                       \
    float f0_ = fmaf((float)(q).x, sS, zN);              \
    float f1_ = fmaf((float)(q).y, sS, zN);              \
    float f2_ = fmaf((float)(q).z, sS, zN);              \
    float f3_ = fmaf((float)(q).w, sS, zN);              \
    U0 = cvt_pk_bf16(f0_, f1_);                          \
    U1 = cvt_pk_bf16(f2_, f3_); }

  auto dequant = [&](const int4 br[4][2], const SZ& sz) {
    const float s0 = sz.s0, zn0 = -(float)sz.z0 * sz.s0;
    const float s1 = sz.s1, zn1 = -(float)sz.z1 * sz.s1;
    #pragma unroll
    for (int f = 0; f < 4; ++f) {
      const float sS = (f < 2) ? s0 : s1;
      const float zN = (f < 2) ? zn0 : zn1;
      BBu b;
      DQH(br[f][0], sS, zN, b.u[0], b.u[1]);
      DQH(br[f][1], sS, zN, b.u[2], b.u[3]);
      bbv[f] = b.v;
    }
  };

  auto compute = [&](int buf) {
    const char* xbase = (const char*)xs[buf];
    #pragma unroll
    for (int mf = 0; mf < 4; ++mf) {
      const int r   = mf * 16 + alo;
      const int swz = (r & 7) << 4;
      const s16x8 af0 = *(const s16x8*)(xbase + r * 128 + (kb_hi ^ swz));
      const s16x8 af1 = *(const s16x8*)(xbase + r * 128 + ((64 + kb_hi) ^ swz));
      acc[mf][0] = __builtin_amdgcn_mfma_f32_16x16x32_bf16(af0, bbv[0], acc[mf][0], 0, 0, 0);
      acc[mf][0] = __builtin_amdgcn_mfma_f32_16x16x32_bf16(af1, bbv[1], acc[mf][0], 0, 0, 0);
      acc[mf][1] = __builtin_amdgcn_mfma_f32_16x16x32_bf16(af0, bbv[2], acc[mf][1], 0, 0, 0);
      acc[mf][1] = __builtin_amdgcn_mfma_f32_16x16x32_bf16(af1, bbv[3], acc[mf][1], 0, 0, 0);
    }
  };

  int4 brA[4][2], brB[4][2];
  SZ szA, szB;

  // ---- prologue: issue order = loadB(0)[12], stage(0)[8], loadB(1)[12] ----
  loadB(0, brA, szA);
  stage_x(0, 0);
  loadB(1, brB, szB);
  VMW(20);                 // brA(0) complete (newer: stage0 8 + loadB1 12)
  dequant(brA, szA);       // bb(0)

  // ---- uniform barrier-free loop: t = 0..61, two steps per iteration ----
  #pragma unroll 1
  for (int tp = 0; tp < 31; ++tp) {
    const int t = tp * 2;
    // even step t
    stage_x(1, t + 1);
    loadB(t + 2, brA, szA);
    VMW(32);               // glds(t) done (newer: loadB(t+1)12 + stage(t+1)8 + loadB(t+2)12)
    compute(0);
    VMW(20);               // brB(t+1) done (newer: stage(t+1)8 + loadB(t+2)12)
    dequant(brB, szB);     // bb(t+1)
    // odd step t+1
    stage_x(0, t + 2);
    loadB(t + 3, brB, szB);
    VMW(32);
    compute(1);
    VMW(20);
    dequant(brA, szA);     // bb(t+2)
  }

  // ---- t = 62 ----
  stage_x(1, 63);
  // lora tail B loads (4 dwordx4); clamp koff for lanes >=32, mask later
  const int koffc = (koff < 16) ? koff : 0;
  const float* lb0 = lb + (size_t)n0c * 16 + koffc;
  const float* lb1 = lb + (size_t)n1c * 16 + koffc;
  int4 tl0 = *(const int4*)(lb0);
  int4 tl1 = *(const int4*)(lb0 + 4);
  int4 tl2 = *(const int4*)(lb1);
  int4 tl3 = *(const int4*)(lb1 + 4);
  VMW(24);                 // glds(62) done (newer: loadB(63)12 + stage(63)8 + tail4)
  compute(0);              // bb(62)
  VMW(12);                 // brB(63) done (newer: stage(63)8 + tail4)
  dequant(brB, szB);       // bb(63)

  // ---- t = 63 ----
  stage_x(0, 64);
  VMW(12);                 // glds(63) done (newer: tail4 + stage(64)8)
  compute(1);
  VMW(8);                  // tail loads done (newer: stage(64)8)
  {
    const bool valid = (lane < 32);
    BBu b0, b1;
    b0.u[0] = valid ? cvt_pk_bf16(__int_as_float(tl0.x), __int_as_float(tl0.y)) : 0u;
    b0.u[1] = valid ? cvt_pk_bf16(__int_as_float(tl0.z), __int_as_float(tl0.w)) : 0u;
    b0.u[2] = valid ? cvt_pk_bf16(__int_as_float(tl1.x), __int_as_float(tl1.y)) : 0u;
    b0.u[3] = valid ? cvt_pk_bf16(__int_as_float(tl1.z), __int_as_float(tl1.w)) : 0u;
    b1.u[0] = valid ? cvt_pk_bf16(__int_as_float(tl2.x), __int_as_float(tl2.y)) : 0u;
    b1.u[1] = valid ? cvt_pk_bf16(__int_as_float(tl2.z), __int_as_float(tl2.w)) : 0u;
    b1.u[2] = valid ? cvt_pk_bf16(__int_as_float(tl3.x), __int_as_float(tl3.y)) : 0u;
    b1.u[3] = valid ? cvt_pk_bf16(__int_as_float(tl3.z), __int_as_float(tl3.w)) : 0u;
    bbv[0] = b0.v;
    bbv[2] = b1.v;
    BBu z; z.u[0] = 0; z.u[1] = 0; z.u[2] = 0; z.u[3] = 0;
    bbv[1] = z.v;        // k-local 32..63 is zero-padded (x pad also 0)
    bbv[3] = z.v;
  }

  // ---- t = 64 (lora columns) ----
  VMW(0);
  compute(0);

  // ---- epilogue: C/D layout col=lane&15, row=(lane>>4)*4+reg ----
  const int rb = m0 + (lane >> 4) * 4;
  const int cb = n0 + alo;
  #pragma unroll
  for (int mf = 0; mf < 4; ++mf) {
    #pragma unroll
    for (int nf = 0; nf < 2; ++nf) {
      #pragma unroll
      for (int j = 0; j < 4; ++j) {
        out[(size_t)(rb + mf * 16 + j) * N_OUT + (cb + nf * 16)] = acc[mf][nf][j];
      }
    }
  }
  #undef DQH
}

extern "C" void kernel_launch(void* const* d_in, const int* in_sizes, int n_in,
                              void* d_out, int out_size, void* d_ws, size_t ws_size,
                              hipStream_t stream) {
  const float* x  = (const float*)d_in[0];
  const int*   qw = (const int*)d_in[1];
  const float* sc = (const float*)d_in[2];
  const int*   zr = (const int*)d_in[3];
  const float* la = (const float*)d_in[4];
  const float* lb = (const float*)d_in[5];
  float* out = (float*)d_out;
  unsigned short* xe = (unsigned short*)d_ws;   // 256*4160*2 = 2.03 MB

  prep_kernel<<<M_TOK, 512, 0, stream>>>(x, la, xe);
  gptq_lora_gemm<<<GRID, 64, 0, stream>>>(qw, sc, zr, lb, xe, out);
}

// Round 7
// 346.553 us; speedup vs baseline: 1.1305x; 1.1305x over previous
//
#include <hip/hip_runtime.h>
#include <stdint.h>

#define M_TOK 256
#define K_IN  4096
#define N_OUT 11008
#define K_EXT 4160              // 4096 + 16 lora + 48 zero pad
#define ROWB  (K_EXT * 2)       // bytes per x_ext row = 8320
#define BM    64
#define BN    64
#define NGL   172               // 11008 / 64
#define GRID  (4 * 4 * NGL)     // mg * kq * ngl = 2752 blocks x 4 waves

typedef __attribute__((ext_vector_type(8))) short s16x8;
typedef __attribute__((ext_vector_type(8))) unsigned short u16x8;
typedef __attribute__((ext_vector_type(4))) float f32x4;

__device__ __forceinline__ unsigned short f2bf(float f) {
  union { float f; unsigned int u; } v; v.f = f;
  unsigned int u = v.u;
  u += 0x7fffu + ((u >> 16) & 1u);   // RNE
  return (unsigned short)(u >> 16);
}

// ---- prep: x fp32 -> bf16 row (stride K_EXT) + lora t2 appended as cols 4096.. ----
__global__ __launch_bounds__(512) void prep_kernel(
    const float* __restrict__ x, const float* __restrict__ la,
    unsigned short* __restrict__ xe)
{
  const int m   = blockIdx.x;
  const int tid = threadIdx.x;
  const int k   = tid * 8;
  const float* xr = x + (size_t)m * K_IN;
  unsigned short* xer = xe + (size_t)m * K_EXT;

  const float4 f0 = *(const float4*)(xr + k);
  const float4 f1 = *(const float4*)(xr + k + 4);
  u16x8 o;
  o[0] = f2bf(f0.x); o[1] = f2bf(f0.y); o[2] = f2bf(f0.z); o[3] = f2bf(f0.w);
  o[4] = f2bf(f1.x); o[5] = f2bf(f1.y); o[6] = f2bf(f1.z); o[7] = f2bf(f1.w);
  *(u16x8*)(xer + k) = o;

  if (tid >= 464) xer[K_IN + 16 + (tid - 464)] = 0;   // zero pad cols 4112..4159

  // lora: wave w owns r = 2w, 2w+1
  const int wave = tid >> 6, lane = tid & 63;
  const float* a0p = la + (size_t)(wave * 2) * K_IN;
  const float* a1p = a0p + K_IN;
  float s0 = 0.f, s1 = 0.f;
  #pragma unroll 4
  for (int it = 0; it < 16; ++it) {
    const int kk = it * 256 + lane * 4;
    const float4 xv = *(const float4*)(xr + kk);
    const float4 a0 = *(const float4*)(a0p + kk);
    const float4 a1 = *(const float4*)(a1p + kk);
    s0 += xv.x * a0.x + xv.y * a0.y + xv.z * a0.z + xv.w * a0.w;
    s1 += xv.x * a1.x + xv.y * a1.y + xv.z * a1.z + xv.w * a1.w;
  }
  #pragma unroll
  for (int off = 32; off > 0; off >>= 1) {
    s0 += __shfl_down(s0, off);
    s1 += __shfl_down(s1, off);
  }
  if (lane == 0) {
    xer[K_IN + wave * 2]     = f2bf(2.0f * s0);   // SCALING folded
    xer[K_IN + wave * 2 + 1] = f2bf(2.0f * s1);
  }
}

// ---------------- main: split-K GEMM, dequant-on-the-fly, atomic combine ----------------
// Block-tile 64M x 64N x K/4. 256 threads (4 waves, 2x2 of 32x32 wave-tiles).
// LDS 32 KB -> 5 blocks/CU co-resident; 2752 blocks -> ~4-5 waves/SIMD.
// kq owns q-steps [kq*16, kq*16+16); kq==3 additionally runs step 64 (lora cols).
__global__ __launch_bounds__(256, 4) void gptq_lora_gemm(
    const int* __restrict__ qw, const float* __restrict__ sc,
    const int* __restrict__ zr, const float* __restrict__ lb,
    const unsigned short* __restrict__ xe, float* __restrict__ out)
{
  __shared__ unsigned short xs[2][BM * 64];   // 2 x 8 KB, XOR-swizzled rows
  __shared__ unsigned short wt[2][BN * 64];   // 2 x 8 KB, XOR-swizzled rows

  const int tid  = threadIdx.x;
  const int wave = tid >> 6;      // 0..3
  const int lane = tid & 63;

  const int bid = blockIdx.x;
  const int mg  = bid & 3;                 // 4 sharers of a q-tile are bid-adjacent
  const int t2  = bid >> 2;
  const int kq  = t2 & 3;
  const int ngl = t2 >> 2;                 // 0..171
  const int m0  = mg * BM;
  const int n0  = ngl * BN;

  const int wm = wave >> 1;       // 0..1 : 32 M-rows
  const int wn = wave & 1;        // 0..1 : 32 N-cols

  // W-staging: row = tid>>2 (0..63), 16 ints at (tid&3)*16
  const int srow  = tid >> 2;
  const int sko   = (tid & 3) * 16;
  const int nglob = n0 + srow;
  const size_t qrow = (size_t)nglob * K_IN;
  const int swz_s   = (srow & 7) << 4;
  const int wt_off0 = srow * 128 + ((sko * 2) ^ swz_s);
  const int wt_off1 = srow * 128 + ((sko * 2 + 16) ^ swz_s);
  const bool lora_ld = (sko == 0);

  f32x4 acc[2][2];
  #pragma unroll
  for (int i = 0; i < 2; ++i) { acc[i][0] = (f32x4)0.f; acc[i][1] = (f32x4)0.f; }

  const int alo   = lane & 15;
  const int kb_hi = (lane >> 4) * 16;
  const char* xb = (const char*)xe;

  auto stage_x = [&](int buf, int step) {
    #pragma unroll
    for (int i = 0; i < 2; ++i) {
      const int base = wave * 2048 + i * 1024;           // wave-uniform LDS base
      const int o    = base + lane * 16;
      const int mrow = o >> 7;                           // 0..63
      const int kb   = o & 127;
      const char* src = xb + (size_t)(m0 + mrow) * ROWB + step * 128
                           + (kb ^ ((mrow & 7) << 4));
      __builtin_amdgcn_global_load_lds(
          (const __attribute__((address_space(1))) void*)src,
          (__attribute__((address_space(3))) void*)((char*)xs[buf] + base),
          16, 0, 0);
    }
  };

  auto load_q = [&](int step, int4 q[4], float& s, float& z) {
    if (step < 64) {
      const int g = step >> 1;               // GROUP_SIZE=128 = 2 k-steps
      s = sc[nglob * 32 + g];
      z = (float)zr[nglob * 32 + g];
      const int* p = qw + qrow + step * 64 + sko;
      q[0] = *(const int4*)(p);
      q[1] = *(const int4*)(p + 4);
      q[2] = *(const int4*)(p + 8);
      q[3] = *(const int4*)(p + 12);
    } else if (lora_ld) {                    // step 64: 16 lora-B floats
      const int4* p = (const int4*)(lb + (size_t)nglob * 16);
      q[0] = p[0]; q[1] = p[1]; q[2] = p[2]; q[3] = p[3];
    }
  };

  auto dequant_write = [&](int step, const int4 q[4], float s, float z, int buf) {
    unsigned short wv[16];
    if (step < 64) {
      #pragma unroll
      for (int i = 0; i < 4; ++i) {
        wv[i * 4 + 0] = f2bf(((float)q[i].x - z) * s);
        wv[i * 4 + 1] = f2bf(((float)q[i].y - z) * s);
        wv[i * 4 + 2] = f2bf(((float)q[i].z - z) * s);
        wv[i * 4 + 3] = f2bf(((float)q[i].w - z) * s);
      }
    } else {
      #pragma unroll
      for (int i = 0; i < 4; ++i) {
        wv[i * 4 + 0] = lora_ld ? f2bf(__int_as_float(q[i].x)) : (unsigned short)0;
        wv[i * 4 + 1] = lora_ld ? f2bf(__int_as_float(q[i].y)) : (unsigned short)0;
        wv[i * 4 + 2] = lora_ld ? f2bf(__int_as_float(q[i].z)) : (unsigned short)0;
        wv[i * 4 + 3] = lora_ld ? f2bf(__int_as_float(q[i].w)) : (unsigned short)0;
      }
    }
    int4 pk0, pk1;
    pk0.x = (int)wv[0]  | ((int)wv[1]  << 16);
    pk0.y = (int)wv[2]  | ((int)wv[3]  << 16);
    pk0.z = (int)wv[4]  | ((int)wv[5]  << 16);
    pk0.w = (int)wv[6]  | ((int)wv[7]  << 16);
    pk1.x = (int)wv[8]  | ((int)wv[9]  << 16);
    pk1.y = (int)wv[10] | ((int)wv[11] << 16);
    pk1.z = (int)wv[12] | ((int)wv[13] << 16);
    pk1.w = (int)wv[14] | ((int)wv[15] << 16);
    *(int4*)((char*)wt[buf] + wt_off0) = pk0;
    *(int4*)((char*)wt[buf] + wt_off1) = pk1;
  };

  auto compute = [&](int buf) {
    s16x8 bfr[2][2];
    #pragma unroll
    for (int nf = 0; nf < 2; ++nf) {
      const int c   = wn * 32 + nf * 16 + alo;
      const int swz = (c & 7) << 4;
      #pragma unroll
      for (int ks = 0; ks < 2; ++ks) {
        const int off = c * 128 + ((ks * 64 + kb_hi) ^ swz);
        bfr[nf][ks] = *(const s16x8*)((const char*)wt[buf] + off);
      }
    }
    #pragma unroll
    for (int mf = 0; mf < 2; ++mf) {
      const int r   = wm * 32 + mf * 16 + alo;
      const int swz = (r & 7) << 4;
      s16x8 af[2];
      #pragma unroll
      for (int ks = 0; ks < 2; ++ks) {
        const int off = r * 128 + ((ks * 64 + kb_hi) ^ swz);
        af[ks] = *(const s16x8*)((const char*)xs[buf] + off);
      }
      #pragma unroll
      for (int nf = 0; nf < 2; ++nf) {
        acc[mf][nf] = __builtin_amdgcn_mfma_f32_16x16x32_bf16(af[0], bfr[nf][0], acc[mf][nf], 0, 0, 0);
        acc[mf][nf] = __builtin_amdgcn_mfma_f32_16x16x32_bf16(af[1], bfr[nf][1], acc[mf][nf], 0, 0, 0);
      }
    }
  };

  const int tbase  = kq * 16;
  const int nsteps = 16 + (kq == 3 ? 1 : 0);   // kq3: steps 48..64 (lora tail at 64)

  // ---- prologue: fill buf 0 ----
  {
    int4 q; float s = 0.f, z = 0.f;
    int4 qq[4];
    load_q(tbase, qq, s, z);
    stage_x(0, tbase);
    dequant_write(tbase, qq, s, z, 0);
    (void)q;
  }
  __syncthreads();

  // ---- simple dbuf loop, 1 barrier/step; TLP (4-5 blocks/CU) hides latency ----
  int buf = 0;
  #pragma unroll 1
  for (int i = 0; i < nsteps; ++i) {
    const int t = tbase + i;
    const bool more = (i + 1 < nsteps);
    int4 qn[4]; float sn = 0.f, zn = 0.f;
    if (more) {
      load_q(t + 1, qn, sn, zn);     // q -> regs (HBM lead time)
      stage_x(buf ^ 1, t + 1);       // x -> LDS (async)
    }
    compute(buf);                    // 8 MFMA
    if (more) dequant_write(t + 1, qn, sn, zn, buf ^ 1);
    __syncthreads();
    buf ^= 1;
  }

  // ---- epilogue: atomic combine of split-K partials ----
  const int rb = m0 + wm * 32 + (lane >> 4) * 4;
  const int cb = n0 + wn * 32 + alo;
  #pragma unroll
  for (int mf = 0; mf < 2; ++mf) {
    #pragma unroll
    for (int nf = 0; nf < 2; ++nf) {
      #pragma unroll
      for (int j = 0; j < 4; ++j) {
        atomicAdd(&out[(size_t)(rb + mf * 16 + j) * N_OUT + (cb + nf * 16)],
                  acc[mf][nf][j]);
      }
    }
  }
}

extern "C" void kernel_launch(void* const* d_in, const int* in_sizes, int n_in,
                              void* d_out, int out_size, void* d_ws, size_t ws_size,
                              hipStream_t stream) {
  const float* x  = (const float*)d_in[0];
  const int*   qw = (const int*)d_in[1];
  const float* sc = (const float*)d_in[2];
  const int*   zr = (const int*)d_in[3];
  const float* la = (const float*)d_in[4];
  const float* lb = (const float*)d_in[5];
  float* out = (float*)d_out;
  unsigned short* xe = (unsigned short*)d_ws;   // 256*4160*2 = 2.03 MB

  hipMemsetAsync(d_out, 0, (size_t)out_size * sizeof(float), stream);  // atomics need zeros
  prep_kernel<<<M_TOK, 512, 0, stream>>>(x, la, xe);
  gptq_lora_gemm<<<GRID, 256, 0, stream>>>(qw, sc, zr, lb, xe, out);
}

// Round 8
// 334.911 us; speedup vs baseline: 1.1698x; 1.0348x over previous
//
#include <hip/hip_runtime.h>
#include <stdint.h>

#define M_TOK 256
#define K_IN  4096
#define N_OUT 11008
#define K_EXT 4160              // 4096 + 16 lora + 48 zero pad
#define ROWB  (K_EXT * 2)       // bytes per x_ext row = 8320
#define BM    64
#define BN    64
#define NGL   172               // 11008 / 64
#define GRID  (4 * 4 * NGL)     // 2752 = 8 xcd * 344; 688 tiles * 4 mg

typedef __attribute__((ext_vector_type(8))) short s16x8;
typedef __attribute__((ext_vector_type(8))) unsigned short u16x8;
typedef __attribute__((ext_vector_type(4))) float f32x4;

__device__ __forceinline__ unsigned short f2bf(float f) {
  union { float f; unsigned int u; } v; v.f = f;
  unsigned int u = v.u;
  u += 0x7fffu + ((u >> 16) & 1u);   // RNE
  return (unsigned short)(u >> 16);
}

// ---- prep: x fp32 -> bf16 row (stride K_EXT) + lora t2 appended as cols 4096.. ----
__global__ __launch_bounds__(512) void prep_kernel(
    const float* __restrict__ x, const float* __restrict__ la,
    unsigned short* __restrict__ xe)
{
  const int m   = blockIdx.x;
  const int tid = threadIdx.x;
  const int k   = tid * 8;
  const float* xr = x + (size_t)m * K_IN;
  unsigned short* xer = xe + (size_t)m * K_EXT;

  const float4 f0 = *(const float4*)(xr + k);
  const float4 f1 = *(const float4*)(xr + k + 4);
  u16x8 o;
  o[0] = f2bf(f0.x); o[1] = f2bf(f0.y); o[2] = f2bf(f0.z); o[3] = f2bf(f0.w);
  o[4] = f2bf(f1.x); o[5] = f2bf(f1.y); o[6] = f2bf(f1.z); o[7] = f2bf(f1.w);
  *(u16x8*)(xer + k) = o;

  if (tid >= 464) xer[K_IN + 16 + (tid - 464)] = 0;   // zero pad cols 4112..4159

  // lora: wave w owns r = 2w, 2w+1
  const int wave = tid >> 6, lane = tid & 63;
  const float* a0p = la + (size_t)(wave * 2) * K_IN;
  const float* a1p = a0p + K_IN;
  float s0 = 0.f, s1 = 0.f;
  #pragma unroll 4
  for (int it = 0; it < 16; ++it) {
    const int kk = it * 256 + lane * 4;
    const float4 xv = *(const float4*)(xr + kk);
    const float4 a0 = *(const float4*)(a0p + kk);
    const float4 a1 = *(const float4*)(a1p + kk);
    s0 += xv.x * a0.x + xv.y * a0.y + xv.z * a0.z + xv.w * a0.w;
    s1 += xv.x * a1.x + xv.y * a1.y + xv.z * a1.z + xv.w * a1.w;
  }
  #pragma unroll
  for (int off = 32; off > 0; off >>= 1) {
    s0 += __shfl_down(s0, off);
    s1 += __shfl_down(s1, off);
  }
  if (lane == 0) {
    xer[K_IN + wave * 2]     = f2bf(2.0f * s0);   // SCALING folded
    xer[K_IN + wave * 2 + 1] = f2bf(2.0f * s1);
  }
}

// ---------------- main: split-K GEMM, dequant-on-the-fly, atomic combine ----------------
// Block-tile 64M x 64N x K/4. 256 threads (4 waves, 2x2 of 32x32 wave-tiles).
// XCD-correct mapping: tile (ngl,kq) owned by ONE xcd; its 4 mg sharers have
// bids congruent mod 8 -> same XCD L2 -> qweight fetched from HBM once.
__global__ __launch_bounds__(256, 5) void gptq_lora_gemm(
    const int* __restrict__ qw, const float* __restrict__ sc,
    const int* __restrict__ zr, const float* __restrict__ lb,
    const unsigned short* __restrict__ xe, float* __restrict__ out)
{
  __shared__ unsigned short xs[2][BM * 64];   // 2 x 8 KB, XOR-swizzled rows
  __shared__ unsigned short wt[2][BN * 64];   // 2 x 8 KB, XOR-swizzled rows

  const int tid  = threadIdx.x;
  const int wave = tid >> 6;      // 0..3
  const int lane = tid & 63;

  // ---- XCD-aware decomposition (round-robin: xcd = bid % 8) ----
  const int bid  = blockIdx.x;
  const int xcd  = bid & 7;
  const int r    = bid >> 3;      // 0..343 (this XCD's local sequence)
  const int mg   = r & 3;         // sharers: bids xcd + 8*(4*tIdx + mg) -> same XCD
  const int tIdx = r >> 2;        // 0..85
  const int tile = xcd * 86 + tIdx;   // 0..687
  const int kq   = tile & 3;
  const int ngl  = tile >> 2;     // 0..171
  const int m0   = mg * BM;
  const int n0   = ngl * BN;

  const int wm = wave >> 1;       // 0..1 : 32 M-rows
  const int wn = wave & 1;        // 0..1 : 32 N-cols

  // W-staging: row = tid>>2 (0..63), 16 ints at (tid&3)*16
  const int srow  = tid >> 2;
  const int sko   = (tid & 3) * 16;
  const int nglob = n0 + srow;
  const size_t qrow = (size_t)nglob * K_IN;
  const int swz_s   = (srow & 7) << 4;
  const int wt_off0 = srow * 128 + ((sko * 2) ^ swz_s);
  const int wt_off1 = srow * 128 + ((sko * 2 + 16) ^ swz_s);
  const bool lora_ld = (sko == 0);

  f32x4 acc[2][2];
  #pragma unroll
  for (int i = 0; i < 2; ++i) { acc[i][0] = (f32x4)0.f; acc[i][1] = (f32x4)0.f; }

  const int alo   = lane & 15;
  const int kb_hi = (lane >> 4) * 16;
  const char* xb = (const char*)xe;

  auto stage_x = [&](int buf, int step) {
    #pragma unroll
    for (int i = 0; i < 2; ++i) {
      const int base = wave * 2048 + i * 1024;           // wave-uniform LDS base
      const int o    = base + lane * 16;
      const int mrow = o >> 7;                           // 0..63
      const int kb   = o & 127;
      const char* src = xb + (size_t)(m0 + mrow) * ROWB + step * 128
                           + (kb ^ ((mrow & 7) << 4));
      __builtin_amdgcn_global_load_lds(
          (const __attribute__((address_space(1))) void*)src,
          (__attribute__((address_space(3))) void*)((char*)xs[buf] + base),
          16, 0, 0);
    }
  };

  auto load_q = [&](int step, int4 q[4], float& s, float& z) {
    if (step < 64) {
      const int g = step >> 1;               // GROUP_SIZE=128 = 2 k-steps
      s = sc[nglob * 32 + g];
      z = (float)zr[nglob * 32 + g];
      const int* p = qw + qrow + step * 64 + sko;
      q[0] = *(const int4*)(p);
      q[1] = *(const int4*)(p + 4);
      q[2] = *(const int4*)(p + 8);
      q[3] = *(const int4*)(p + 12);
    } else if (lora_ld) {                    // step 64: 16 lora-B floats
      const int4* p = (const int4*)(lb + (size_t)nglob * 16);
      q[0] = p[0]; q[1] = p[1]; q[2] = p[2]; q[3] = p[3];
    }
  };

  auto dequant_write = [&](int step, const int4 q[4], float s, float z, int buf) {
    unsigned short wv[16];
    if (step < 64) {
      #pragma unroll
      for (int i = 0; i < 4; ++i) {
        wv[i * 4 + 0] = f2bf(((float)q[i].x - z) * s);
        wv[i * 4 + 1] = f2bf(((float)q[i].y - z) * s);
        wv[i * 4 + 2] = f2bf(((float)q[i].z - z) * s);
        wv[i * 4 + 3] = f2bf(((float)q[i].w - z) * s);
      }
    } else {
      #pragma unroll
      for (int i = 0; i < 4; ++i) {
        wv[i * 4 + 0] = lora_ld ? f2bf(__int_as_float(q[i].x)) : (unsigned short)0;
        wv[i * 4 + 1] = lora_ld ? f2bf(__int_as_float(q[i].y)) : (unsigned short)0;
        wv[i * 4 + 2] = lora_ld ? f2bf(__int_as_float(q[i].z)) : (unsigned short)0;
        wv[i * 4 + 3] = lora_ld ? f2bf(__int_as_float(q[i].w)) : (unsigned short)0;
      }
    }
    int4 pk0, pk1;
    pk0.x = (int)wv[0]  | ((int)wv[1]  << 16);
    pk0.y = (int)wv[2]  | ((int)wv[3]  << 16);
    pk0.z = (int)wv[4]  | ((int)wv[5]  << 16);
    pk0.w = (int)wv[6]  | ((int)wv[7]  << 16);
    pk1.x = (int)wv[8]  | ((int)wv[9]  << 16);
    pk1.y = (int)wv[10] | ((int)wv[11] << 16);
    pk1.z = (int)wv[12] | ((int)wv[13] << 16);
    pk1.w = (int)wv[14] | ((int)wv[15] << 16);
    *(int4*)((char*)wt[buf] + wt_off0) = pk0;
    *(int4*)((char*)wt[buf] + wt_off1) = pk1;
  };

  auto compute = [&](int buf) {
    s16x8 bfr[2][2];
    #pragma unroll
    for (int nf = 0; nf < 2; ++nf) {
      const int c   = wn * 32 + nf * 16 + alo;
      const int swz = (c & 7) << 4;
      #pragma unroll
      for (int ks = 0; ks < 2; ++ks) {
        const int off = c * 128 + ((ks * 64 + kb_hi) ^ swz);
        bfr[nf][ks] = *(const s16x8*)((const char*)wt[buf] + off);
      }
    }
    #pragma unroll
    for (int mf = 0; mf < 2; ++mf) {
      const int r2  = wm * 32 + mf * 16 + alo;
      const int swz = (r2 & 7) << 4;
      s16x8 af[2];
      #pragma unroll
      for (int ks = 0; ks < 2; ++ks) {
        const int off = r2 * 128 + ((ks * 64 + kb_hi) ^ swz);
        af[ks] = *(const s16x8*)((const char*)xs[buf] + off);
      }
      #pragma unroll
      for (int nf = 0; nf < 2; ++nf) {
        acc[mf][nf] = __builtin_amdgcn_mfma_f32_16x16x32_bf16(af[0], bfr[nf][0], acc[mf][nf], 0, 0, 0);
        acc[mf][nf] = __builtin_amdgcn_mfma_f32_16x16x32_bf16(af[1], bfr[nf][1], acc[mf][nf], 0, 0, 0);
      }
    }
  };

  const int tbase  = kq * 16;
  const int nsteps = 16 + (kq == 3 ? 1 : 0);   // kq3: steps 48..64 (lora tail at 64)

  // ---- prologue: fill buf 0 ----
  {
    int4 qq[4]; float s = 0.f, z = 0.f;
    load_q(tbase, qq, s, z);
    stage_x(0, tbase);
    dequant_write(tbase, qq, s, z, 0);
  }
  __syncthreads();

  // ---- simple dbuf loop, 1 barrier/step; TLP (5 blocks/CU) hides latency ----
  int buf = 0;
  #pragma unroll 1
  for (int i = 0; i < nsteps; ++i) {
    const int t = tbase + i;
    const bool more = (i + 1 < nsteps);
    int4 qn[4]; float sn = 0.f, zn = 0.f;
    if (more) {
      load_q(t + 1, qn, sn, zn);     // q -> regs (HBM lead time)
      stage_x(buf ^ 1, t + 1);       // x -> LDS (async)
    }
    compute(buf);                    // 8 MFMA
    if (more) dequant_write(t + 1, qn, sn, zn, buf ^ 1);
    __syncthreads();
    buf ^= 1;
  }

  // ---- epilogue: atomic combine of split-K partials ----
  const int rb = m0 + wm * 32 + (lane >> 4) * 4;
  const int cb = n0 + wn * 32 + alo;
  #pragma unroll
  for (int mf = 0; mf < 2; ++mf) {
    #pragma unroll
    for (int nf = 0; nf < 2; ++nf) {
      #pragma unroll
      for (int j = 0; j < 4; ++j) {
        atomicAdd(&out[(size_t)(rb + mf * 16 + j) * N_OUT + (cb + nf * 16)],
                  acc[mf][nf][j]);
      }
    }
  }
}

extern "C" void kernel_launch(void* const* d_in, const int* in_sizes, int n_in,
                              void* d_out, int out_size, void* d_ws, size_t ws_size,
                              hipStream_t stream) {
  const float* x  = (const float*)d_in[0];
  const int*   qw = (const int*)d_in[1];
  const float* sc = (const float*)d_in[2];
  const int*   zr = (const int*)d_in[3];
  const float* la = (const float*)d_in[4];
  const float* lb = (const float*)d_in[5];
  float* out = (float*)d_out;
  unsigned short* xe = (unsigned short*)d_ws;   // 256*4160*2 = 2.03 MB

  hipMemsetAsync(d_out, 0, (size_t)out_size * sizeof(float), stream);  // atomics need zeros
  prep_kernel<<<M_TOK, 512, 0, stream>>>(x, la, xe);
  gptq_lora_gemm<<<GRID, 256, 0, stream>>>(qw, sc, zr, lb, xe, out);
}